// Round 7
// baseline (416.664 us; speedup 1.0000x reference)
//
#include <hip/hip_runtime.h>

typedef unsigned short u16;
typedef unsigned int u32;
typedef __attribute__((ext_vector_type(8))) short s16x8;
typedef __attribute__((ext_vector_type(4))) float f32x4;

#define GAS __attribute__((address_space(1)))
#define LAS __attribute__((address_space(3)))

// ---- constants ----
#define BB 4
#define LL 8192
#define DD 1024
#define NH 16
#define HD 64
#define MROWS (BB * LL)          // 32768
#define NWBT 2064                // 1024 Q + 1024 K + 16 WvS rows

__device__ __forceinline__ u16 f2bf(float f) {
  u32 u = __builtin_bit_cast(u32, f);
  u32 r = (u + 0x7FFFu + ((u >> 16) & 1u)) >> 16;
  return (u16)r;
}
__device__ __forceinline__ float bf2f(u32 lo) {
  return __builtin_bit_cast(float, lo << 16);
}

__device__ __forceinline__ void async16(const void* g, void* l) {
  __builtin_amdgcn_global_load_lds((const GAS u32*)g, (LAS u32*)l, 16, 0, 0);
}

// mask encoding modes: 0 = int32, 1 = float32, 2 = uint8
__device__ __forceinline__ bool get_mask(const void* mp, int row, int mode) {
  if (mode == 2) return ((const unsigned char*)mp)[row] != 0;
  if (mode == 1) return ((const float*)mp)[row] != 0.f;
  return ((const int*)mp)[row] != 0;
}

// Build WbT[n][k] = W{q,k}[k][n mod 1024] as bf16 (transposed, 32x32 LDS tiles)
__global__ void build_wbt(const float* __restrict__ Wq, const float* __restrict__ Wk,
                          u16* __restrict__ WbT) {
  __shared__ float t[32][33];
  const int n0 = blockIdx.x * 32;  // 0..2047
  const int k0 = blockIdx.y * 32;  // 0..1023
  const float* W = (n0 >> 10) == 0 ? Wq : Wk;
  const int nloc = n0 & 1023;
  const int tx = threadIdx.x, ty = threadIdx.y;  // 32 x 8
#pragma unroll
  for (int j = 0; j < 32; j += 8)
    t[ty + j][tx] = W[(size_t)(k0 + ty + j) * DD + nloc + tx];
  __syncthreads();
#pragma unroll
  for (int j = 0; j < 32; j += 8)
    WbT[(size_t)(n0 + ty + j) * DD + k0 + tx] = f2bf(t[tx][ty + j]);
}

// Merged small-prep kernel (105 blocks x 256):
//  blocks 0..63   : WbT rows 2048..2063  WvS[h][k] = sum_j Wv[k][h*64+j]
//  blocks 64..72  : bcat  [0..1023]=bq, [1024..2047]=bk, [2048+h]=sum bv
//  blocks 73..104 : mask dtype detection (8192 words)
__global__ void build_aux(const float* __restrict__ Wv, const float* __restrict__ bq,
                          const float* __restrict__ bk, const float* __restrict__ bv,
                          const u32* __restrict__ m,
                          u16* __restrict__ WbT, float* __restrict__ bcat,
                          int* __restrict__ flag) {
  const int blk = blockIdx.x;
  const int tid = threadIdx.x;
  if (blk < 64) {
    int i = blk * 256 + tid;  // 0..16383: k = i>>4, h = i&15
    int k = i >> 4, h = i & 15;
    float s = 0.f;
    const float* p = Wv + (size_t)k * DD + h * HD;
#pragma unroll 8
    for (int j = 0; j < 64; ++j) s += p[j];
    WbT[(size_t)(2048 + h) * DD + k] = f2bf(s);
  } else if (blk < 73) {
    int i = (blk - 64) * 256 + tid;
    if (i < 1024) bcat[i] = bq[i];
    else if (i < 2048) bcat[i] = bk[i - 1024];
    else if (i < 2064) {
      float s = 0.f;
      const float* p = bv + (i - 2048) * HD;
#pragma unroll 8
      for (int j = 0; j < 64; ++j) s += p[j];
      bcat[i] = s;
    }
  } else {
    int i = (blk - 73) * 256 + tid;  // 0..8191
    u32 v = m[i];
    int f = 0;
    if (v == 0x3F800000u) f = 1;       // looks like float 1.0
    else if (v > 1u) f = 2;            // packed bytes -> uint8
    if (f) atomicMax(flag, f);
  }
}

// Fused query fp32->bf16 conversion + sV GEMM, v3 (barrier-free, verified r4/r6).
__global__ __launch_bounds__(256) void prep_q(
    const float* __restrict__ query, const u16* __restrict__ WbT,
    const float* __restrict__ bcat, const void* __restrict__ maskp,
    const int* __restrict__ mmode,
    u16* __restrict__ qb, float* __restrict__ sV) {
  __shared__ float sVp[2][16][16];
  const int tid = threadIdx.x;
  const int lane = tid & 63;
  const int w = tid >> 6;          // 0..3
  const int wl = w >> 1;           // local row-tile 0/1
  const int ks = w & 1;            // K-half 0/1
  const int l15 = lane & 15, l16 = lane >> 4;
  const int row0 = blockIdx.x * 32 + wl * 16;
  const int arow = row0 + l15;     // this lane's A-frag row

  const float* qrow = query + (size_t)arow * DD + ks * 512 + l16 * 8;
  u16* qbrow = qb + (size_t)arow * DD + ks * 512 + l16 * 8;
  const u16* wrow = WbT + (size_t)(2048 + l15) * DD + ks * 512 + l16 * 8;

  f32x4 acc = {};
#pragma unroll
  for (int mac = 0; mac < 2; ++mac) {      // 2 macro-steps x 8 k-steps x 32k
    float4 qv[16];
    s16x8 wv[8];
#pragma unroll
    for (int s = 0; s < 8; ++s) {
      const int off = mac * 256 + s * 32;  // element offset within K-half
      qv[s * 2] = *(const float4*)(qrow + off);
      qv[s * 2 + 1] = *(const float4*)(qrow + off + 4);
      wv[s] = *(const s16x8*)(wrow + off);
    }
#pragma unroll
    for (int s = 0; s < 8; ++s) {
      s16x8 o;
      o[0] = (short)f2bf(qv[s * 2].x);     o[1] = (short)f2bf(qv[s * 2].y);
      o[2] = (short)f2bf(qv[s * 2].z);     o[3] = (short)f2bf(qv[s * 2].w);
      o[4] = (short)f2bf(qv[s * 2 + 1].x); o[5] = (short)f2bf(qv[s * 2 + 1].y);
      o[6] = (short)f2bf(qv[s * 2 + 1].z); o[7] = (short)f2bf(qv[s * 2 + 1].w);
      *(s16x8*)(qbrow + mac * 256 + s * 32) = o;
      acc = __builtin_amdgcn_mfma_f32_16x16x32_bf16(o, wv[s], acc, 0, 0, 0);
    }
  }

  // combine K-halves: ks=1 parks partial in LDS; ks=0 adds, masks, stores
  if (ks == 1) {
#pragma unroll
    for (int r = 0; r < 4; ++r) sVp[wl][l16 * 4 + r][l15] = acc[r];
  }
  __syncthreads();
  if (ks == 0) {
    const int mode = *mmode;
#pragma unroll
    for (int r = 0; r < 4; ++r) {
      const int row = row0 + l16 * 4 + r;
      const bool msk = get_mask(maskp, row, mode);
      float v = acc[r] + sVp[wl][l16 * 4 + r][l15] + bcat[2048 + l15];
      sV[(size_t)row * NH + l15] = msk ? 0.f : v;
    }
  }
}

// ---------------------------------------------------------------------------
// 128x512-tile projection GEMM, v4: wide per-wave tile for LDS-read intensity.
// 8 waves (2M x 4N), per-wave output 64x128 -> acc[4][8] = 128 VGPR;
// __launch_bounds__(512,2) -> 256-reg cap, 1 block/CU (occupancy proven
// irrelevant in r2/r6; the shared limiter is LDS-read + barrier density).
// vs r6: LDS bytes per FLOP -25% (Mw+Nw: 128 -> 192 for 2x FLOP),
// barriers per FLOP -50% (16 MFMA per barrier-pair instead of 8).
// BK=32; LDS 80 KB = 2 x (A 128x32 = 8 KB) + 2 x (B 512x32 = 32 KB).
// Race-free restage (r6 schedule, counts re-derived: A=1 load/thr, B=4):
// B1 in P0, A0 in P1, B0 in P2, A1 in P3; prologue vmcnt(5); steady
// vmcnt(1) at P1/P3; vmcnt(0) only in the peeled final iteration.
// Grid 512 (%8==0, bijective XCD swizzle).
// phase arg: 1 = K section (fused kv reduction), 0 = Q section (out write).
// ---------------------------------------------------------------------------
#define AOFF(buf) ((buf) * 4096)           // A unit: 4096 u16 = 8 KB
#define BOFF(buf) (8192 + (buf) * 16384)   // B unit: 16384 u16 = 32 KB

__global__ __launch_bounds__(512, 2) void gemm_qkv(
    const u16* __restrict__ qb, const u16* __restrict__ WbT,
    const float* __restrict__ bcat, const void* __restrict__ maskp,
    const int* __restrict__ mmode,
    const float* __restrict__ sV, float* __restrict__ kv,
    float* __restrict__ out, int phase) {
  __shared__ __align__(16) u16 lds[40960];  // 80 KB
  const int tid = threadIdx.x;
  const int lane = tid & 63;
  const int w = tid >> 6;          // 0..7
  const int wm = w & 1, wn = w >> 1;
  const int l15 = lane & 15, l16 = lane >> 4;

  // T1: bijective XCD swizzle (512 blocks, 512 % 8 == 0)
  const int bid = blockIdx.x;
  const int swz = (bid & 7) * 64 + (bid >> 3);
  const int mt = swz >> 1;         // 0..255
  const int nt = swz & 1;          // 0..1
  const int row0 = mt * 128;
  const int col0 = (phase ? 1024 : 0) + nt * 512;

  f32x4 acc[4][8] = {};

// A-unit: 128 rows x 4 chunks = 512 -> 1 load/thread
#define STAGE_A(buf, kt) do {                                               \
    int row_ = tid >> 2, slot_ = tid & 3;                                   \
    int c_ = slot_ ^ ((row_ >> 1) & 3);                                     \
    async16(qb + (size_t)(row0 + row_) * DD + (kt) * 32 + c_ * 8,           \
            lds + AOFF(buf) + tid * 8);                                     \
  } while (0)

// B-unit: 512 rows x 4 chunks = 2048 -> 4 loads/thread
#define STAGE_B(buf, kt) do {                                               \
    _Pragma("unroll")                                                       \
    for (int j_ = 0; j_ < 4; ++j_) {                                        \
      int li_ = tid + j_ * 512;                                             \
      int row_ = li_ >> 2, slot_ = li_ & 3;                                 \
      int c_ = slot_ ^ ((row_ >> 1) & 3);                                   \
      async16(WbT + (size_t)(col0 + row_) * DD + (kt) * 32 + c_ * 8,        \
              lds + BOFF(buf) + li_ * 8);                                   \
    }                                                                       \
  } while (0)

#define LDA(buf, a) do {                                                    \
    _Pragma("unroll")                                                       \
    for (int mi_ = 0; mi_ < 4; ++mi_) {                                     \
      int r_ = wm * 64 + mi_ * 16 + l15;                                    \
      a[mi_] = *(const s16x8*)(lds + AOFF(buf) + r_ * 32 +                  \
                               ((l16 ^ ((r_ >> 1) & 3)) * 8));              \
    }                                                                       \
  } while (0)

// 4 B-frags for n-half nb (64 cols)
#define LDB4(buf, nb, b) do {                                               \
    _Pragma("unroll")                                                       \
    for (int q_ = 0; q_ < 4; ++q_) {                                        \
      int r_ = wn * 128 + (nb) * 64 + q_ * 16 + l15;                        \
      b[q_] = *(const s16x8*)(lds + BOFF(buf) + r_ * 32 +                   \
                              ((l16 ^ ((r_ >> 1) & 3)) * 8));               \
    }                                                                       \
  } while (0)

#define MM(a, b, nb) do {                                                   \
    __builtin_amdgcn_s_setprio(1);                                          \
    _Pragma("unroll")                                                       \
    for (int mi_ = 0; mi_ < 4; ++mi_) {                                     \
      _Pragma("unroll")                                                     \
      for (int q_ = 0; q_ < 4; ++q_) {                                      \
        acc[mi_][(nb)*4 + q_] = __builtin_amdgcn_mfma_f32_16x16x32_bf16(    \
            a[mi_], b[q_], acc[mi_][(nb)*4 + q_], 0, 0, 0);                 \
      }                                                                     \
    }                                                                       \
    __builtin_amdgcn_s_setprio(0);                                          \
  } while (0)

#define BAR() __builtin_amdgcn_s_barrier()
#define VMW1() asm volatile("s_waitcnt vmcnt(1)" ::: "memory")
#define VMW5() asm volatile("s_waitcnt vmcnt(5)" ::: "memory")
#define VMW0() asm volatile("s_waitcnt vmcnt(0)" ::: "memory")

  // prologue: tiles 0,1 -> A0,B0,A1,B1 (1+4+1+4 = 10 loads/thread)
  STAGE_A(0, 0); STAGE_B(0, 0); STAGE_A(1, 1); STAGE_B(1, 1);
  VMW5();   // retire A0,B0 (tile 0 ready); A1,B1 (5 loads) still in flight
  BAR();

  for (int t = 0; t < 30; t += 2) {
    s16x8 a[4], b[4];
    // P0: read A0 + B0 nh0 (tile t); restage B1 <- t+1 (free since prev P3)
    LDA(0, a); LDB4(0, 0, b);
    if (t > 0) STAGE_B(1, t + 1);
    BAR(); MM(a, b, 0); BAR();
    // P1: read B0 nh1; restage A0 <- t+2; wait tile t+1 (A1,B1) landed
    LDB4(0, 1, b);
    STAGE_A(0, t + 2);
    BAR(); MM(a, b, 1); VMW1(); BAR();
    // P2: read A1 + B1 nh0 (tile t+1); restage B0 <- t+2
    LDA(1, a); LDB4(1, 0, b);
    STAGE_B(0, t + 2);
    BAR(); MM(a, b, 0); BAR();
    // P3: read B1 nh1; restage A1 <- t+3; wait tile t+2 (A0,B0) landed
    LDB4(1, 1, b);
    STAGE_A(1, t + 3);
    BAR(); MM(a, b, 1); VMW1(); BAR();
  }

  {  // peeled final iteration t=30 (tiles 30,31; stage only B1 <- 31)
    s16x8 a[4], b[4];
    LDA(0, a); LDB4(0, 0, b);
    STAGE_B(1, 31);
    BAR(); MM(a, b, 0); BAR();
    LDB4(0, 1, b);
    BAR(); MM(a, b, 1); VMW0(); BAR();   // drain: A1,B1 (tile 31) landed
    LDA(1, a); LDB4(1, 0, b);
    BAR(); MM(a, b, 0); BAR();
    LDB4(1, 1, b);
    BAR(); MM(a, b, 1);
  }

  // ---- epilogue ----
  const int mode = *mmode;
  const int lanec = lane & 15, laneq = lane >> 4;
  const int wcol0 = col0 + wn * 128;  // wave spans two 64-col head groups
  const int b_ = row0 >> 13;          // batch (rows never cross batch)

  if (phase == 1) {
    // K section with fused kv_sum reduction
    const int h0 = (wcol0 - 1024) >> 6;  // head for nj<4; h0+1 for nj>=4
    float pc[8] = {0.f, 0.f, 0.f, 0.f, 0.f, 0.f, 0.f, 0.f};
#pragma unroll
    for (int mi = 0; mi < 4; ++mi) {
#pragma unroll
      for (int r = 0; r < 4; ++r) {
        const int row = row0 + wm * 64 + mi * 16 + laneq * 4 + r;
        const bool msk = get_mask(maskp, row, mode);
        if (!msk) {
          const float sv0 = sV[(size_t)row * NH + h0];
          const float sv1 = sV[(size_t)row * NH + h0 + 1];
#pragma unroll
          for (int nj = 0; nj < 8; ++nj) {
            const int col = wcol0 + nj * 16 + lanec;
            float v = acc[mi][nj][r] + bcat[col];
            float phi = v > 0.f ? v + 1.f : __expf(v);
            pc[nj] += phi * (nj < 4 ? sv0 : sv1);
          }
        }
      }
    }
#pragma unroll
    for (int nj = 0; nj < 8; ++nj) {
      pc[nj] += __shfl_xor(pc[nj], 16);
      pc[nj] += __shfl_xor(pc[nj], 32);
    }
    if (laneq == 0) {
#pragma unroll
      for (int nj = 0; nj < 8; ++nj) {
        const int colk = wcol0 - 1024 + nj * 16 + lanec;  // 0..1023
        atomicAdd(&kv[b_ * DD + colk], pc[nj]);
      }
    }
  } else {
    // Q section -> out = phi * kv_sum (finalize fused)
    float kvv[8];
#pragma unroll
    for (int nj = 0; nj < 8; ++nj)
      kvv[nj] = kv[b_ * DD + wcol0 + nj * 16 + lanec];
#pragma unroll
    for (int mi = 0; mi < 4; ++mi) {
#pragma unroll
      for (int r = 0; r < 4; ++r) {
        const int row = row0 + wm * 64 + mi * 16 + laneq * 4 + r;
#pragma unroll
        for (int nj = 0; nj < 8; ++nj) {
          const int col = wcol0 + nj * 16 + lanec;
          float v = acc[mi][nj][r] + bcat[col];
          float phi = v > 0.f ? v + 1.f : __expf(v);
          out[(size_t)row * DD + col] = phi * kvv[nj];
        }
      }
    }
  }
}

extern "C" void kernel_launch(void* const* d_in, const int* in_sizes, int n_in,
                              void* d_out, int out_size, void* d_ws, size_t ws_size,
                              hipStream_t stream) {
  const float* query = (const float*)d_in[0];
  const void* maskp = d_in[1];
  const float* Wq = (const float*)d_in[2];
  const float* bq = (const float*)d_in[3];
  const float* Wk = (const float*)d_in[4];
  const float* bk = (const float*)d_in[5];
  const float* Wv = (const float*)d_in[6];
  const float* bv = (const float*)d_in[7];
  float* out = (float*)d_out;

  char* ws = (char*)d_ws;
  u16* qb = (u16*)ws;            ws += (size_t)MROWS * DD * 2;      // 64 MB
  u16* WbT = (u16*)ws;           ws += (size_t)NWBT * DD * 2;       // ~4.2 MB
  float* sV = (float*)ws;        ws += (size_t)MROWS * NH * 4;      // 2 MB
  float* bcat = (float*)ws;      ws += (size_t)NWBT * 4;
  float* kv = (float*)ws;        ws += (size_t)BB * DD * 4;         // 16 KB
  int* mflag = (int*)ws;         ws += 256;

  // zero kv_sum + mask-mode flag (contiguous in workspace)
  hipMemsetAsync(kv, 0, (size_t)BB * DD * 4 + 256, stream);

  build_wbt<<<dim3(2048 / 32, DD / 32), dim3(32, 8), 0, stream>>>(Wq, Wk, WbT);
  build_aux<<<105, 256, 0, stream>>>(Wv, bq, bk, bv, (const u32*)maskp, WbT, bcat, mflag);
  // fused cvt + sV (barrier-free v3)
  prep_q<<<MROWS / 32, 256, 0, stream>>>(query, WbT, bcat, maskp, mflag, qb, sV);
  // K phase first: kv_sum (fused reduction, no phiK materialization)
  gemm_qkv<<<512, 512, 0, stream>>>(qb, WbT, bcat, maskp, mflag, sV, kv, out, 1);
  // Q phase: out = phiQ * kv_sum (finalize fused, no phiQ materialization)
  gemm_qkv<<<512, 512, 0, stream>>>(qb, WbT, bcat, maskp, mflag, sV, kv, out, 0);
}